// Round 5
// baseline (13.396 us; speedup 1.0000x reference)
//
#include <hip/hip_runtime.h>

// Quanvolution — closed-form, 4 patches per thread, cached (non-NT) I/O.
//   z0 = cos(w0)cos(w3)*c0 - sin(w3)*s0*s2
//   z1 = cos(w1)*c1
//   z2 = cos(w0)*c0*c2
//   z3 = cos(w0)cos(w4)*c0*c2*c3 - sin(w4)*s3
// ci=cos(pi xi), si=sin(pi xi) over the 2x2 patch (x0,x1 / x2,x3).
// x in [0,1) -> trig in revolutions: v_sin/v_cos(0.5*x), no range reduction.
// Output (16.8 MB) and input (16.8 MB) both fit Infinity Cache -> plain
// cached loads/stores (NT hints regressed: they force HBM traffic).
//
// x: [64,1,256,256] f32, weights: [1,5] f32, out: [64,128,128,4] f32.

typedef float f32x4 __attribute__((ext_vector_type(4)));

__global__ __launch_bounds__(256) void quanv_kernel(
    const float* __restrict__ x, const float* __restrict__ w,
    float* __restrict__ out)
{
    int t = blockIdx.x * 256 + threadIdx.x;   // 0 .. 262143
    int kk = (t & 31) * 4;          // first patch col (0..124, step 4)
    int j  = (t >> 5) & 127;        // patch row
    int b  = t >> 12;               // batch

    const float* xp = x + (((size_t)b * 256 + 2 * j) * 256 + 2 * kk);
    // row 2j:   x0 of patches A..D interleaved with x1
    f32x4 r0a = *reinterpret_cast<const f32x4*>(xp);
    f32x4 r0b = *reinterpret_cast<const f32x4*>(xp + 4);
    // row 2j+1: x2, x3
    f32x4 r1a = *reinterpret_cast<const f32x4*>(xp + 256);
    f32x4 r1b = *reinterpret_cast<const f32x4*>(xp + 260);

    // uniform weight coefficients via fast trig (args ~N(0,1), ample accuracy)
    float sw0, cw0; __sincosf(w[0], &sw0, &cw0);
    float sw1, cw1; __sincosf(w[1], &sw1, &cw1);
    float sw3, cw3; __sincosf(w[3], &sw3, &cw3);
    float sw4, cw4; __sincosf(w[4], &sw4, &cw4);
    float A = cw0 * cw3;
    float E = cw0 * cw4;

    float x0[4] = { r0a.x, r0a.z, r0b.x, r0b.z };
    float x1[4] = { r0a.y, r0a.w, r0b.y, r0b.w };
    float x2[4] = { r1a.x, r1a.z, r1b.x, r1b.z };
    float x3[4] = { r1a.y, r1a.w, r1b.y, r1b.w };

    f32x4 o[4];
    #pragma unroll
    for (int p = 0; p < 4; ++p) {
        float c0 = __builtin_amdgcn_cosf(0.5f * x0[p]);
        float s0 = __builtin_amdgcn_sinf(0.5f * x0[p]);
        float c1 = __builtin_amdgcn_cosf(0.5f * x1[p]);
        float c2 = __builtin_amdgcn_cosf(0.5f * x2[p]);
        float s2 = __builtin_amdgcn_sinf(0.5f * x2[p]);
        float c3 = __builtin_amdgcn_cosf(0.5f * x3[p]);
        float s3 = __builtin_amdgcn_sinf(0.5f * x3[p]);
        float c0c2 = c0 * c2;
        o[p] = (f32x4){ A * c0 - sw3 * s0 * s2,
                        cw1 * c1,
                        cw0 * c0c2,
                        E * c0c2 * c3 - sw4 * s3 };
    }

    f32x4* op = reinterpret_cast<f32x4*>(out + (size_t)t * 16);
    op[0] = o[0]; op[1] = o[1]; op[2] = o[2]; op[3] = o[3];
}

extern "C" void kernel_launch(void* const* d_in, const int* in_sizes, int n_in,
                              void* d_out, int out_size, void* d_ws, size_t ws_size,
                              hipStream_t stream) {
    const float* x = (const float*)d_in[0];
    const float* w = (const float*)d_in[1];
    float* out = (float*)d_out;
    const int threads = 64 * 128 * 32;   // 4 patches per thread
    quanv_kernel<<<threads / 256, 256, 0, stream>>>(x, w, out);
}

// Round 6
// 11.111 us; speedup vs baseline: 1.2056x; 1.2056x over previous
//
#include <hip/hip_runtime.h>

// Quanvolution — closed-form, 2 patches per thread (R4 mapping), cached stores.
//   z0 = cos(w0)cos(w3)*c0 - sin(w3)*s0*s2
//   z1 = cos(w1)*c1
//   z2 = cos(w0)*c0*c2
//   z3 = cos(w0)cos(w4)*c0*c2*c3 - sin(w4)*s3
// ci=cos(pi xi), si=sin(pi xi) over the 2x2 patch (x0,x1 / x2,x3).
// x in [0,1) -> trig in revolutions: v_sin/v_cos(0.5*x), no range reduction.
// Output (16.8 MB) fits Infinity Cache -> plain cached stores (NT hint
// forces HBM writes; cached write-back completes at L3 speed).
//
// x: [64,1,256,256] f32, weights: [1,5] f32, out: [64,128,128,4] f32.

typedef float f32x4 __attribute__((ext_vector_type(4)));

__global__ __launch_bounds__(256) void quanv_kernel(
    const float* __restrict__ x, const float* __restrict__ w,
    float* __restrict__ out)
{
    int t = blockIdx.x * 256 + threadIdx.x;       // 0 .. 524287
    int kk = (t & 63) * 2;          // first patch col (0..126 even)
    int j  = (t >> 6) & 127;        // patch row
    int b  = t >> 13;               // batch

    const float* xp = x + (((size_t)b * 256 + 2 * j) * 256 + 2 * kk);
    f32x4 r0 = *reinterpret_cast<const f32x4*>(xp);        // row 2j  : xA0 xA1 xB0 xB1
    f32x4 r1 = *reinterpret_cast<const f32x4*>(xp + 256);  // row 2j+1: xA2 xA3 xB2 xB3

    // uniform weight coefficients via fast trig (args ~N(0,1), ample accuracy)
    float sw0, cw0; __sincosf(w[0], &sw0, &cw0);
    float sw1, cw1; __sincosf(w[1], &sw1, &cw1);
    float sw3, cw3; __sincosf(w[3], &sw3, &cw3);
    float sw4, cw4; __sincosf(w[4], &sw4, &cw4);
    float A = cw0 * cw3;
    float E = cw0 * cw4;

    f32x4 oA, oB;
    {   // patch A: x0=r0.x x1=r0.y x2=r1.x x3=r1.y
        float c0 = __builtin_amdgcn_cosf(0.5f * r0.x);
        float s0 = __builtin_amdgcn_sinf(0.5f * r0.x);
        float c1 = __builtin_amdgcn_cosf(0.5f * r0.y);
        float c2 = __builtin_amdgcn_cosf(0.5f * r1.x);
        float s2 = __builtin_amdgcn_sinf(0.5f * r1.x);
        float c3 = __builtin_amdgcn_cosf(0.5f * r1.y);
        float s3 = __builtin_amdgcn_sinf(0.5f * r1.y);
        float c0c2 = c0 * c2;
        oA = (f32x4){ A * c0 - sw3 * s0 * s2,
                      cw1 * c1,
                      cw0 * c0c2,
                      E * c0c2 * c3 - sw4 * s3 };
    }
    {   // patch B: x0=r0.z x1=r0.w x2=r1.z x3=r1.w
        float c0 = __builtin_amdgcn_cosf(0.5f * r0.z);
        float s0 = __builtin_amdgcn_sinf(0.5f * r0.z);
        float c1 = __builtin_amdgcn_cosf(0.5f * r0.w);
        float c2 = __builtin_amdgcn_cosf(0.5f * r1.z);
        float s2 = __builtin_amdgcn_sinf(0.5f * r1.z);
        float c3 = __builtin_amdgcn_cosf(0.5f * r1.w);
        float s3 = __builtin_amdgcn_sinf(0.5f * r1.w);
        float c0c2 = c0 * c2;
        oB = (f32x4){ A * c0 - sw3 * s0 * s2,
                      cw1 * c1,
                      cw0 * c0c2,
                      E * c0c2 * c3 - sw4 * s3 };
    }

    f32x4* op = reinterpret_cast<f32x4*>(out + (size_t)t * 8);
    op[0] = oA;
    op[1] = oB;
}

extern "C" void kernel_launch(void* const* d_in, const int* in_sizes, int n_in,
                              void* d_out, int out_size, void* d_ws, size_t ws_size,
                              hipStream_t stream) {
    const float* x = (const float*)d_in[0];
    const float* w = (const float*)d_in[1];
    float* out = (float*)d_out;
    const int threads = 64 * 128 * 64;   // 2 patches per thread
    quanv_kernel<<<threads / 256, 256, 0, stream>>>(x, w, out);
}

// Round 7
// 9.942 us; speedup vs baseline: 1.3474x; 1.1176x over previous
//
#include <hip/hip_runtime.h>

// Quanvolution — closed-form, 2 patches per thread (best R4 mapping),
// NT stores + fast weight trig (union of best-measured components).
//   z0 = cos(w0)cos(w3)*c0 - sin(w3)*s0*s2
//   z1 = cos(w1)*c1
//   z2 = cos(w0)*c0*c2
//   z3 = cos(w0)cos(w4)*c0*c2*c3 - sin(w4)*s3
// ci=cos(pi xi), si=sin(pi xi) over the 2x2 patch (x0,x1 / x2,x3).
// x in [0,1) -> trig in revolutions: v_sin/v_cos(0.5*x), no range reduction.
//
// x: [64,1,256,256] f32, weights: [1,5] f32, out: [64,128,128,4] f32.
// History: R2 (1 patch/thr, cached)=10.7; R4 (2/thr, NT, libm)=10.3;
// R5 (4/thr, strided)=13.4; R6 (2/thr, cached, fast trig)=11.1.
// Plateau ~10.3-11.1 = ~5.2us traffic floor + dispatch/ramp overhead.

typedef float f32x4 __attribute__((ext_vector_type(4)));

__global__ __launch_bounds__(256) void quanv_kernel(
    const float* __restrict__ x, const float* __restrict__ w,
    float* __restrict__ out)
{
    int t = blockIdx.x * 256 + threadIdx.x;       // 0 .. 524287
    int kk = (t & 63) * 2;          // first patch col (0..126 even)
    int j  = (t >> 6) & 127;        // patch row
    int b  = t >> 13;               // batch

    const float* xp = x + (((size_t)b * 256 + 2 * j) * 256 + 2 * kk);
    f32x4 r0 = *reinterpret_cast<const f32x4*>(xp);        // row 2j  : xA0 xA1 xB0 xB1
    f32x4 r1 = *reinterpret_cast<const f32x4*>(xp + 256);  // row 2j+1: xA2 xA3 xB2 xB3

    // uniform weight coefficients via fast trig (args ~N(0,1), ample accuracy)
    float sw0, cw0; __sincosf(w[0], &sw0, &cw0);
    float sw1, cw1; __sincosf(w[1], &sw1, &cw1);
    float sw3, cw3; __sincosf(w[3], &sw3, &cw3);
    float sw4, cw4; __sincosf(w[4], &sw4, &cw4);
    float A = cw0 * cw3;
    float E = cw0 * cw4;

    f32x4 oA, oB;
    {   // patch A: x0=r0.x x1=r0.y x2=r1.x x3=r1.y
        float c0 = __builtin_amdgcn_cosf(0.5f * r0.x);
        float s0 = __builtin_amdgcn_sinf(0.5f * r0.x);
        float c1 = __builtin_amdgcn_cosf(0.5f * r0.y);
        float c2 = __builtin_amdgcn_cosf(0.5f * r1.x);
        float s2 = __builtin_amdgcn_sinf(0.5f * r1.x);
        float c3 = __builtin_amdgcn_cosf(0.5f * r1.y);
        float s3 = __builtin_amdgcn_sinf(0.5f * r1.y);
        float c0c2 = c0 * c2;
        oA = (f32x4){ A * c0 - sw3 * s0 * s2,
                      cw1 * c1,
                      cw0 * c0c2,
                      E * c0c2 * c3 - sw4 * s3 };
    }
    {   // patch B: x0=r0.z x1=r0.w x2=r1.z x3=r1.w
        float c0 = __builtin_amdgcn_cosf(0.5f * r0.z);
        float s0 = __builtin_amdgcn_sinf(0.5f * r0.z);
        float c1 = __builtin_amdgcn_cosf(0.5f * r0.w);
        float c2 = __builtin_amdgcn_cosf(0.5f * r1.z);
        float s2 = __builtin_amdgcn_sinf(0.5f * r1.z);
        float c3 = __builtin_amdgcn_cosf(0.5f * r1.w);
        float s3 = __builtin_amdgcn_sinf(0.5f * r1.w);
        float c0c2 = c0 * c2;
        oB = (f32x4){ A * c0 - sw3 * s0 * s2,
                      cw1 * c1,
                      cw0 * c0c2,
                      E * c0c2 * c3 - sw4 * s3 };
    }

    f32x4* op = reinterpret_cast<f32x4*>(out + (size_t)t * 8);
    __builtin_nontemporal_store(oA, op);
    __builtin_nontemporal_store(oB, op + 1);
}

extern "C" void kernel_launch(void* const* d_in, const int* in_sizes, int n_in,
                              void* d_out, int out_size, void* d_ws, size_t ws_size,
                              hipStream_t stream) {
    const float* x = (const float*)d_in[0];
    const float* w = (const float*)d_in[1];
    float* out = (float*)d_out;
    const int threads = 64 * 128 * 64;   // 2 patches per thread
    quanv_kernel<<<threads / 256, 256, 0, stream>>>(x, w, out);
}